// Round 1
// baseline (1472.816 us; speedup 1.0000x reference)
//
#include <hip/hip_runtime.h>
#include <hip/hip_bf16.h>
#include <math.h>

#define TTOK 4096
#define HD   1536
#define IDIM 768
#define NE   64
#define KSEL 8
#define CAP  1024
#define ECAP (NE * CAP)

typedef unsigned int uint32;
typedef __bf16 bf16;
typedef __attribute__((ext_vector_type(8))) __bf16 bf16x8;
typedef __attribute__((ext_vector_type(4))) __bf16 bf16x4;
typedef __attribute__((ext_vector_type(4))) float f32x4;

// ---------------------------------------------------------------- cast x -> bf16
__global__ __launch_bounds__(256) void k_cast(const float* __restrict__ x, bf16* __restrict__ xb) {
    int i = (blockIdx.x * 256 + threadIdx.x) * 8;
    float4 a = *(const float4*)(x + i);
    float4 b = *(const float4*)(x + i + 4);
    bf16x8 o;
    o[0] = (bf16)a.x; o[1] = (bf16)a.y; o[2] = (bf16)a.z; o[3] = (bf16)a.w;
    o[4] = (bf16)b.x; o[5] = (bf16)b.y; o[6] = (bf16)b.z; o[7] = (bf16)b.w;
    *(bf16x8*)(xb + i) = o;
}

// ---------------------------------------------------------------- router logits (fp64 accumulate)
// 8 tokens per block; thread = (token tr = tid>>5, expert pair er = (tid&31)*2)
__global__ __launch_bounds__(256) void k_router(const float* __restrict__ x, const float* __restrict__ gw,
                                                double* __restrict__ logits) {
    __shared__ float Xt[8 * HD];   // 48 KB
    int t0 = blockIdx.x * 8;
    int tid = threadIdx.x;
    {
        const float4* src = (const float4*)(x + (size_t)t0 * HD);
        float4* dst = (float4*)Xt;
        for (int u = tid; u < 8 * HD / 4; u += 256) dst[u] = src[u];
    }
    __syncthreads();
    int tr = tid >> 5;
    int er = (tid & 31) * 2;
    const float* xr = Xt + tr * HD;
    const float* g0 = gw + (size_t)er * HD;
    const float* g1 = g0 + HD;
    double c0 = 0.0, c1 = 0.0;
    for (int k = 0; k < HD; k += 4) {
        float4 a  = *(const float4*)(xr + k);
        float4 b0 = *(const float4*)(g0 + k);
        float4 b1 = *(const float4*)(g1 + k);
        c0 += (double)a.x * b0.x + (double)a.y * b0.y + (double)a.z * b0.z + (double)a.w * b0.w;
        c1 += (double)a.x * b1.x + (double)a.y * b1.y + (double)a.z * b1.z + (double)a.w * b1.w;
    }
    double* lp = logits + (size_t)(t0 + tr) * NE + er;
    lp[0] = c0; lp[1] = c1;
}

// ---------------------------------------------------------------- top-8 + slot assignment
__global__ __launch_bounds__(64) void k_topk(const double* __restrict__ logits, const float* __restrict__ bias,
                                             float* __restrict__ wv, uint32* __restrict__ rowtok,
                                             uint32* __restrict__ tkof, int* __restrict__ cnt) {
    int t = blockIdx.x, lane = threadIdx.x;
    double lg = logits[(size_t)t * NE + lane];
    double sig = 1.0 / (1.0 + exp(-lg));          // raw score (combine weight source)
    double sel = sig + (double)bias[lane];        // selection score
    double mysig = sig;
    double wsum = 0.0;
    int my_e = -1; double my_s = 0.0;
    for (int k = 0; k < KSEL; ++k) {
        double v = sel; int ei = lane;
        #pragma unroll
        for (int off = 32; off > 0; off >>= 1) {
            double ov = __shfl_down(v, off);
            int    oi = __shfl_down(ei, off);
            if (ov > v || (ov == v && oi < ei)) { v = ov; ei = oi; }  // lowest index on tie (jax)
        }
        ei = __shfl(ei, 0);                // winner expert, broadcast
        double sw = __shfl(mysig, ei);     // its raw score
        wsum += sw;
        if (lane == k) { my_e = ei; my_s = sw; }
        if (lane == ei) sel = -1.0e300;
    }
    if (lane < KSEL) {
        float w = (float)(my_s / wsum);
        int tk = t * KSEL + lane;
        int pos = atomicAdd(cnt + my_e, 1);
        if (pos < CAP) {
            rowtok[my_e * CAP + pos] = (uint32)t;
            tkof  [my_e * CAP + pos] = (uint32)tk;
            wv[tk] = w;
        } else {
            wv[tk] = 0.0f;   // dropped (never in practice): zero contribution like reference
        }
    }
}

// ---------------------------------------------------------------- gemm1: Hc = silu(x@Wg^T) * (x@Wu^T)
// grid 6144 = 64e x 8mt x 12nt; decode keeps same-(e,nt) m-tiles on one XCD (ids == mod 8)
__global__ __launch_bounds__(256) void k_gemm1(const bf16* __restrict__ xb,
        const float* __restrict__ wg, const float* __restrict__ wu,
        const uint32* __restrict__ rowtok, const int* __restrict__ cnt,
        bf16* __restrict__ hc) {
    int id = blockIdx.x;
    int G  = ((id >> 6) << 3) | (id & 7);   // 0..767 = e*12+nt
    int mt = (id >> 3) & 7;
    int e  = G / 12, nt = G % 12;
    int n_rows = cnt[e];
    if (mt * 128 >= n_rows) return;

    __shared__ __align__(16) bf16 As[4 * 128 * 8];  // [kc][m][8]  8KB
    __shared__ __align__(16) bf16 Bg[4 * 64 * 8];   // [kc][n][8]  4KB
    __shared__ __align__(16) bf16 Bu[4 * 64 * 8];

    int tid = threadIdx.x;
    int am  = tid >> 2;       // 0..63
    int akc = tid & 3;        // 0..3
    int r0 = mt * 128 + am, r1 = r0 + 64;
    uint32 tok0 = (r0 < n_rows) ? rowtok[e * CAP + r0] : 0u;
    uint32 tok1 = (r1 < n_rows) ? rowtok[e * CAP + r1] : 0u;
    const bf16* a0p = xb + (size_t)tok0 * HD + akc * 8;
    const bf16* a1p = xb + (size_t)tok1 * HD + akc * 8;
    const float* wgp = wg + ((size_t)e * IDIM + nt * 64 + am) * HD + akc * 8;
    const float* wup = wu + ((size_t)e * IDIM + nt * 64 + am) * HD + akc * 8;

    int wave = tid >> 6, lane = tid & 63;
    int wm = wave & 1, wn = wave >> 1;
    int q = lane >> 4, r = lane & 15;

    f32x4 zero = {0.f, 0.f, 0.f, 0.f};
    f32x4 accg[4][2], accu[4][2];
    #pragma unroll
    for (int s = 0; s < 4; ++s)
        #pragma unroll
        for (int t2 = 0; t2 < 2; ++t2) { accg[s][t2] = zero; accu[s][t2] = zero; }

    bf16* asw0 = As + ((akc * 128) + am) * 8;
    bf16* asw1 = As + ((akc * 128) + am + 64) * 8;
    bf16* bgw  = Bg + ((akc * 64) + am) * 8;
    bf16* buw  = Bu + ((akc * 64) + am) * 8;

    for (int k0 = 0; k0 < HD; k0 += 32) {
        uint4 va0 = *(const uint4*)(a0p + k0);
        uint4 va1 = *(const uint4*)(a1p + k0);
        float4 gA = *(const float4*)(wgp + k0);
        float4 gB = *(const float4*)(wgp + k0 + 4);
        float4 uA = *(const float4*)(wup + k0);
        float4 uB = *(const float4*)(wup + k0 + 4);
        __syncthreads();
        *(uint4*)asw0 = va0;
        *(uint4*)asw1 = va1;
        bf16x8 pg, pu;
        pg[0]=(bf16)gA.x; pg[1]=(bf16)gA.y; pg[2]=(bf16)gA.z; pg[3]=(bf16)gA.w;
        pg[4]=(bf16)gB.x; pg[5]=(bf16)gB.y; pg[6]=(bf16)gB.z; pg[7]=(bf16)gB.w;
        pu[0]=(bf16)uA.x; pu[1]=(bf16)uA.y; pu[2]=(bf16)uA.z; pu[3]=(bf16)uA.w;
        pu[4]=(bf16)uB.x; pu[5]=(bf16)uB.y; pu[6]=(bf16)uB.z; pu[7]=(bf16)uB.w;
        *(bf16x8*)bgw = pg;
        *(bf16x8*)buw = pu;
        __syncthreads();
        bf16x8 af[4], bgf[2], buf2[2];
        #pragma unroll
        for (int s = 0; s < 4; ++s)
            af[s] = *(const bf16x8*)(As + (q * 128 + wm * 64 + s * 16 + r) * 8);
        #pragma unroll
        for (int t2 = 0; t2 < 2; ++t2) {
            bgf[t2]  = *(const bf16x8*)(Bg + (q * 64 + wn * 32 + t2 * 16 + r) * 8);
            buf2[t2] = *(const bf16x8*)(Bu + (q * 64 + wn * 32 + t2 * 16 + r) * 8);
        }
        #pragma unroll
        for (int s = 0; s < 4; ++s)
            #pragma unroll
            for (int t2 = 0; t2 < 2; ++t2) {
                accg[s][t2] = __builtin_amdgcn_mfma_f32_16x16x32_bf16(af[s], bgf[t2],  accg[s][t2], 0, 0, 0);
                accu[s][t2] = __builtin_amdgcn_mfma_f32_16x16x32_bf16(af[s], buf2[t2], accu[s][t2], 0, 0, 0);
            }
    }
    size_t rowbase = (size_t)e * CAP + mt * 128;
    #pragma unroll
    for (int s = 0; s < 4; ++s)
        #pragma unroll
        for (int t2 = 0; t2 < 2; ++t2)
            #pragma unroll
            for (int rg = 0; rg < 4; ++rg) {
                int row = wm * 64 + s * 16 + q * 4 + rg;
                int col = nt * 64 + wn * 32 + t2 * 16 + r;
                float g = accg[s][t2][rg], u = accu[s][t2][rg];
                float h = g / (1.f + __expf(-g)) * u;   // silu(g)*u
                hc[(rowbase + row) * (size_t)IDIM + col] = (bf16)h;
            }
}

// ---------------------------------------------------------------- gemm2: Yw[tk] = Hc @ Wd^T  (scatter rows)
__global__ __launch_bounds__(256) void k_gemm2(const bf16* __restrict__ hc,
        const float* __restrict__ wd, const uint32* __restrict__ tkof,
        const int* __restrict__ cnt, bf16* __restrict__ yw) {
    int id = blockIdx.x;
    int G  = ((id >> 6) << 3) | (id & 7);
    int mt = (id >> 3) & 7;
    int e  = G / 12, nt = G % 12;
    int n_rows = cnt[e];
    if (mt * 128 >= n_rows) return;

    __shared__ __align__(16) bf16 As[4 * 128 * 8];
    __shared__ __align__(16) bf16 Bs[4 * 128 * 8];

    int tid = threadIdx.x;
    int am = tid >> 2, akc = tid & 3;
    const bf16*  a0p = hc + ((size_t)e * CAP + mt * 128 + am) * IDIM + akc * 8;
    const bf16*  a1p = a0p + (size_t)64 * IDIM;
    const float* b0p = wd + ((size_t)e * HD + nt * 128 + am) * IDIM + akc * 8;
    const float* b1p = b0p + (size_t)64 * IDIM;

    int wave = tid >> 6, lane = tid & 63;
    int wm = wave & 1, wn = wave >> 1;
    int q = lane >> 4, r = lane & 15;

    f32x4 zero = {0.f, 0.f, 0.f, 0.f};
    f32x4 acc[4][4];
    #pragma unroll
    for (int s = 0; s < 4; ++s)
        #pragma unroll
        for (int t2 = 0; t2 < 4; ++t2) acc[s][t2] = zero;

    bf16* asw0 = As + (akc * 128 + am) * 8;
    bf16* asw1 = As + (akc * 128 + am + 64) * 8;
    bf16* bsw0 = Bs + (akc * 128 + am) * 8;
    bf16* bsw1 = Bs + (akc * 128 + am + 64) * 8;

    for (int k0 = 0; k0 < IDIM; k0 += 32) {
        uint4 va0 = *(const uint4*)(a0p + k0);
        uint4 va1 = *(const uint4*)(a1p + k0);
        float4 cA = *(const float4*)(b0p + k0);
        float4 cB = *(const float4*)(b0p + k0 + 4);
        float4 dA = *(const float4*)(b1p + k0);
        float4 dB = *(const float4*)(b1p + k0 + 4);
        __syncthreads();
        *(uint4*)asw0 = va0;
        *(uint4*)asw1 = va1;
        bf16x8 p0, p1;
        p0[0]=(bf16)cA.x; p0[1]=(bf16)cA.y; p0[2]=(bf16)cA.z; p0[3]=(bf16)cA.w;
        p0[4]=(bf16)cB.x; p0[5]=(bf16)cB.y; p0[6]=(bf16)cB.z; p0[7]=(bf16)cB.w;
        p1[0]=(bf16)dA.x; p1[1]=(bf16)dA.y; p1[2]=(bf16)dA.z; p1[3]=(bf16)dA.w;
        p1[4]=(bf16)dB.x; p1[5]=(bf16)dB.y; p1[6]=(bf16)dB.z; p1[7]=(bf16)dB.w;
        *(bf16x8*)bsw0 = p0;
        *(bf16x8*)bsw1 = p1;
        __syncthreads();
        bf16x8 af[4], bf4[4];
        #pragma unroll
        for (int s = 0; s < 4; ++s)
            af[s] = *(const bf16x8*)(As + (q * 128 + wm * 64 + s * 16 + r) * 8);
        #pragma unroll
        for (int t2 = 0; t2 < 4; ++t2)
            bf4[t2] = *(const bf16x8*)(Bs + (q * 128 + wn * 64 + t2 * 16 + r) * 8);
        #pragma unroll
        for (int s = 0; s < 4; ++s)
            #pragma unroll
            for (int t2 = 0; t2 < 4; ++t2)
                acc[s][t2] = __builtin_amdgcn_mfma_f32_16x16x32_bf16(af[s], bf4[t2], acc[s][t2], 0, 0, 0);
    }
    uint32 tkx[4][4];
    #pragma unroll
    for (int s = 0; s < 4; ++s)
        #pragma unroll
        for (int rg = 0; rg < 4; ++rg) {
            int row = mt * 128 + wm * 64 + s * 16 + q * 4 + rg;
            tkx[s][rg] = (row < n_rows) ? tkof[e * CAP + row] : 0xFFFFFFFFu;
        }
    #pragma unroll
    for (int s = 0; s < 4; ++s)
        #pragma unroll
        for (int t2 = 0; t2 < 4; ++t2)
            #pragma unroll
            for (int rg = 0; rg < 4; ++rg) {
                if (tkx[s][rg] != 0xFFFFFFFFu) {
                    int col = nt * 128 + wn * 64 + t2 * 16 + r;
                    yw[(size_t)tkx[s][rg] * HD + col] = (bf16)acc[s][t2][rg];
                }
            }
}

// ---------------------------------------------------------------- combine: out[t] = sum_k w_k * Yw[t,k]
__global__ __launch_bounds__(256) void k_combine(const bf16* __restrict__ yw,
        const float* __restrict__ wv, float* __restrict__ out) {
    int t = blockIdx.x, tid = threadIdx.x;
    __shared__ float w8[KSEL];
    if (tid < KSEL) w8[tid] = wv[t * KSEL + tid];
    __syncthreads();
    for (int c0 = tid * 4; c0 < HD; c0 += 1024) {
        float a0 = 0.f, a1 = 0.f, a2 = 0.f, a3 = 0.f;
        #pragma unroll
        for (int k = 0; k < KSEL; ++k) {
            bf16x4 v = *(const bf16x4*)(yw + ((size_t)(t * KSEL + k)) * HD + c0);
            float wk = w8[k];
            a0 += wk * (float)v[0];
            a1 += wk * (float)v[1];
            a2 += wk * (float)v[2];
            a3 += wk * (float)v[3];
        }
        float4 o = {a0, a1, a2, a3};
        *(float4*)(out + (size_t)t * HD + c0) = o;
    }
}

// ---------------------------------------------------------------- launch
extern "C" void kernel_launch(void* const* d_in, const int* in_sizes, int n_in,
                              void* d_out, int out_size, void* d_ws, size_t ws_size,
                              hipStream_t stream) {
    const float* x  = (const float*)d_in[0];
    const float* gw = (const float*)d_in[1];
    const float* rb = (const float*)d_in[2];
    const float* wg = (const float*)d_in[3];
    const float* wu = (const float*)d_in[4];
    const float* wd = (const float*)d_in[5];
    float* out = (float*)d_out;

    char* ws = (char*)d_ws;
    size_t off = 0;
    auto alloc = [&](size_t bytes) -> void* {
        off = (off + 255) & ~(size_t)255;
        void* p = ws + off;
        off += bytes;
        return p;
    };
    bf16*   xb     = (bf16*)   alloc((size_t)TTOK * HD * 2);        // 12.6 MB
    double* logits = (double*) alloc((size_t)TTOK * NE * 8);        //  2.1 MB
    float*  wv     = (float*)  alloc((size_t)TTOK * KSEL * 4);      //  0.13 MB
    uint32* rowtok = (uint32*) alloc((size_t)ECAP * 4);             //  0.26 MB
    uint32* tkof   = (uint32*) alloc((size_t)ECAP * 4);             //  0.26 MB
    int*    cnt    = (int*)    alloc(256);
    bf16*   hc     = (bf16*)   alloc((size_t)ECAP * IDIM * 2);      // 100.7 MB
    bf16*   yw     = (bf16*)   alloc((size_t)TTOK * KSEL * HD * 2); // 100.7 MB
    (void)ws_size; (void)in_sizes; (void)n_in; (void)out_size; (void)rb;

    hipMemsetAsync(cnt, 0, 256, stream);
    k_cast   <<<TTOK * HD / 2048, 256, 0, stream>>>(x, xb);
    k_router <<<TTOK / 8,         256, 0, stream>>>(x, gw, logits);
    k_topk   <<<TTOK,             64,  0, stream>>>(logits, rb, wv, rowtok, tkof, cnt);
    k_gemm1  <<<6144,             256, 0, stream>>>(xb, wg, wu, rowtok, cnt, hc);
    k_gemm2  <<<6144,             256, 0, stream>>>(hc, wd, tkof, cnt, yw);
    k_combine<<<TTOK,             256, 0, stream>>>(yw, wv, out);
}